// Round 1
// baseline (411.129 us; speedup 1.0000x reference)
//
#include <hip/hip_runtime.h>
#include <stdint.h>

typedef short bf16x8 __attribute__((ext_vector_type(8)));
typedef float f32x4 __attribute__((ext_vector_type(4)));
typedef unsigned int uint4v __attribute__((ext_vector_type(4)));
typedef unsigned short ushort4v __attribute__((ext_vector_type(4)));
typedef float float4v __attribute__((ext_vector_type(4)));

#define MROWS 18464      // 32*577
#define MPAD  18560      // 145*128
#define SEQ   577
#define CDIM  1024
#define QV_LD 2048
#define W1ELEMS (2048*1024)
#define W2ELEMS (1024*1024)

__device__ __forceinline__ unsigned short f2bf(float f) {
  unsigned int u = __float_as_uint(f);
  u += 0x7fffu + ((u >> 16) & 1u);   // RNE
  return (unsigned short)(u >> 16);
}

__device__ __forceinline__ void load_lds16(const void* g, void* lds) {
  __builtin_amdgcn_global_load_lds(
      (const __attribute__((address_space(1))) unsigned int*)(uint64_t)(uintptr_t)g,
      (__attribute__((address_space(3))) unsigned int*)(unsigned int)(uintptr_t)lds,
      16, 0, 0);
}

// ---------------- LayerNorm: x fp32 -> z bf16; pad rows zeroed ----------------
__global__ __launch_bounds__(256) void ln_kernel(const float* __restrict__ x,
                                                 const float* __restrict__ g,
                                                 const float* __restrict__ b,
                                                 unsigned short* __restrict__ z) {
  const int row = blockIdx.x;
  const int t = threadIdx.x;
  unsigned short* zp = z + (size_t)row * CDIM + t * 4;
  if (row >= MROWS) { *(ushort4v*)zp = (ushort4v)0; return; }
  const float4v v = *(const float4v*)(x + (size_t)row * CDIM + t * 4);
  float s  = v[0] + v[1] + v[2] + v[3];
  float ss = v[0]*v[0] + v[1]*v[1] + v[2]*v[2] + v[3]*v[3];
  #pragma unroll
  for (int off = 1; off < 64; off <<= 1) { s += __shfl_xor(s, off); ss += __shfl_xor(ss, off); }
  __shared__ float rs[4], rss[4];
  const int w = t >> 6, l = t & 63;
  if (l == 0) { rs[w] = s; rss[w] = ss; }
  __syncthreads();
  s = rs[0] + rs[1] + rs[2] + rs[3];
  ss = rss[0] + rss[1] + rss[2] + rss[3];
  const float mu = s * (1.0f / CDIM);
  const float var = ss * (1.0f / CDIM) - mu * mu;
  const float rstd = rsqrtf(var + 1e-5f);
  const float4v gv = *(const float4v*)(g + t * 4);
  const float4v bv = *(const float4v*)(b + t * 4);
  ushort4v o;
  #pragma unroll
  for (int j = 0; j < 4; ++j) o[j] = f2bf((v[j] - mu) * rstd * gv[j] + bv[j]);
  *(ushort4v*)zp = o;
}

// -------- pack+convert weights: wqv[2048][1024] (q rows 0..1023 = w_in 0..1023,
// v rows 1024..2047 = w_in 2048..3071), wo[1024][1024] --------
__global__ __launch_bounds__(256) void conv_kernel(const float* __restrict__ w_in,
                                                   const float* __restrict__ w_out,
                                                   unsigned short* __restrict__ wqv,
                                                   unsigned short* __restrict__ wo) {
  const int e = (blockIdx.x * 256 + threadIdx.x) * 4;
  float4v v; unsigned short* dst;
  if (e < W1ELEMS) {
    const int row = e >> 10;
    const int srow = row < 1024 ? row : row + 1024;
    v = *(const float4v*)(w_in + (size_t)srow * 1024 + (e & 1023));
    dst = wqv + e;
  } else {
    const int e2 = e - W1ELEMS;
    v = *(const float4v*)(w_out + e2);
    dst = wo + e2;
  }
  ushort4v o;
  #pragma unroll
  for (int j = 0; j < 4; ++j) o[j] = f2bf(v[j]);
  *(ushort4v*)dst = o;
}

// ---------------- GEMM: C[m][c] = sum_k A[m][k]*B[c][k] + bias[c] ----------------
// A [MPAD][1024] bf16, B [NC][1024] bf16. 128x128 tile, BK=64, 4 waves.
// MODE 0: bf16 out, ldc=NC, q/v bias map.  MODE 1: fp32 out, row<MROWS guard.
template<int MODE>
__global__ __launch_bounds__(256) void gemm_kernel(const unsigned short* __restrict__ A,
                                                   const unsigned short* __restrict__ B,
                                                   const float* __restrict__ bias,
                                                   void* __restrict__ outp,
                                                   const int NC) {
  __shared__ char smem[32768];  // A tile 16KB @0, B tile 16KB @16384; row stride 128B
  const int t = threadIdx.x;
  const int w = t >> 6, l = t & 63;
  const int m0 = blockIdx.y * 128, n0 = blockIdx.x * 128;
  const int wr = w >> 1, wc = w & 1;

  f32x4 acc[4][4];
  #pragma unroll
  for (int i = 0; i < 4; ++i)
    #pragma unroll
    for (int j = 0; j < 4; ++j) acc[i][j] = (f32x4)0.0f;

  const int srow = l >> 3;                                         // row within 8-row call
  const int scol = ((((l & 7) * 16) ^ ((srow & 7) << 4)) >> 1);    // pre-swizzled fetch col (elems)
  const int fr = l & 15;
  const int fb = (l >> 4) * 16;
  const int sw = (l & 7) << 4;                                     // read-side swizzle

  for (int kb = 0; kb < 16; ++kb) {
    __syncthreads();
    const int k0 = kb * 64;
    #pragma unroll
    for (int c = 0; c < 4; ++c) {
      const int ra = w * 32 + c * 8;
      load_lds16(A + (size_t)(m0 + ra + srow) * 1024 + k0 + scol, smem + ra * 128);
      load_lds16(B + (size_t)(n0 + ra + srow) * 1024 + k0 + scol, smem + 16384 + ra * 128);
    }
    __syncthreads();
    #pragma unroll
    for (int kk = 0; kk < 2; ++kk) {
      bf16x8 af[4], bf[4];
      #pragma unroll
      for (int i = 0; i < 4; ++i)
        af[i] = *(const bf16x8*)(smem + (wr * 64 + i * 16 + fr) * 128 + ((kk * 64 + fb) ^ sw));
      #pragma unroll
      for (int j = 0; j < 4; ++j)
        bf[j] = *(const bf16x8*)(smem + 16384 + (wc * 64 + j * 16 + fr) * 128 + ((kk * 64 + fb) ^ sw));
      #pragma unroll
      for (int i = 0; i < 4; ++i)
        #pragma unroll
        for (int j = 0; j < 4; ++j)
          acc[i][j] = __builtin_amdgcn_mfma_f32_16x16x32_bf16(af[i], bf[j], acc[i][j], 0, 0, 0);
    }
  }

  #pragma unroll
  for (int i = 0; i < 4; ++i) {
    #pragma unroll
    for (int j = 0; j < 4; ++j) {
      const int col = n0 + wc * 64 + j * 16 + fr;
      float bv;
      if (MODE == 0) bv = (col < 1024) ? bias[col] : bias[1024 + col];  // v bias at b_in[2048+..]
      else           bv = bias[col];
      #pragma unroll
      for (int r = 0; r < 4; ++r) {
        const int row = m0 + wr * 64 + i * 16 + (l >> 4) * 4 + r;
        const float val = acc[i][j][r] + bv;
        if (MODE == 0) {
          ((unsigned short*)outp)[(size_t)row * NC + col] = f2bf(val);
        } else {
          if (row < MROWS) ((float*)outp)[(size_t)row * NC + col] = val;
        }
      }
    }
  }
}

// ---------------- flash attention, k = q ('qq'), per (n,h,64-row block) ----------------
__global__ __launch_bounds__(256) void attn_kernel(const unsigned short* __restrict__ qv,
                                                   unsigned short* __restrict__ out) {
  __shared__ char smem[32768];  // Qt@0 8KB, Kt@8192, Vt@16384 (transposed), P@24576 2KB/wave
  const int qb = blockIdx.x;    // 0..9
  const int nh = blockIdx.y;    // 0..511
  const int n = nh >> 4, h = nh & 15;
  const int t = threadIdx.x;
  const int w = t >> 6, l = t & 63;
  const size_t rowbase = (size_t)n * SEQ;
  const unsigned short* qbase = qv + h * 64;

  // Q tile 64x64, swizzled, zero-fill invalid rows
  #pragma unroll
  for (int p = 0; p < 2; ++p) {
    const int e = p * 256 + t;
    const int r = e >> 3;
    const int cb = (e & 7) * 16;
    const int s = qb * 64 + r;
    uint4v val = (uint4v)0u;
    if (s < SEQ) val = *(const uint4v*)(qbase + (rowbase + s) * QV_LD + (cb >> 1));
    *(uint4v*)(smem + r * 128 + (cb ^ ((r & 7) << 4))) = val;
  }
  __syncthreads();

  const int fr = l & 15;
  const int fb = (l >> 4) * 16;
  const int sw = (l & 7) << 4;
  bf16x8 aq[2];
  #pragma unroll
  for (int kk = 0; kk < 2; ++kk)
    aq[kk] = *(const bf16x8*)(smem + (w * 16 + fr) * 128 + ((kk * 64 + fb) ^ sw));

  f32x4 acc[4];
  #pragma unroll
  for (int cf = 0; cf < 4; ++cf) acc[cf] = (f32x4)0.0f;
  float m_run[4], l_run[4];
  #pragma unroll
  for (int r = 0; r < 4; ++r) { m_run[r] = -__builtin_inff(); l_run[r] = 0.0f; }

  for (int kb = 0; kb < 10; ++kb) {
    __syncthreads();
    // K tile (rows of q)
    #pragma unroll
    for (int p = 0; p < 2; ++p) {
      const int e = p * 256 + t;
      const int r = e >> 3;
      const int cb = (e & 7) * 16;
      const int s = kb * 64 + r;
      uint4v val = (uint4v)0u;
      if (s < SEQ) val = *(const uint4v*)(qbase + (rowbase + s) * QV_LD + (cb >> 1));
      *(uint4v*)(smem + 8192 + r * 128 + (cb ^ ((r & 7) << 4))) = val;
    }
    // V tile, transposed into Vt[d][seq]
    {
      const int sp = t & 31, dc = t >> 5;
      const int s0 = kb * 64 + 2 * sp;
      uint4v v0 = (uint4v)0u, v1 = (uint4v)0u;
      if (s0 < SEQ)     v0 = *(const uint4v*)(qbase + 1024 + (rowbase + s0) * QV_LD + dc * 8);
      if (s0 + 1 < SEQ) v1 = *(const uint4v*)(qbase + 1024 + (rowbase + s0 + 1) * QV_LD + dc * 8);
      const unsigned short* p0 = (const unsigned short*)&v0;
      const unsigned short* p1 = (const unsigned short*)&v1;
      #pragma unroll
      for (int j = 0; j < 8; ++j) {
        const int d = dc * 8 + j;
        const unsigned int pk = (unsigned int)p0[j] | ((unsigned int)p1[j] << 16);
        *(unsigned int*)(smem + 16384 + d * 128 + ((sp * 4) ^ ((d & 7) << 4))) = pk;
      }
    }
    __syncthreads();

    // S = Q K^T (wave tile 16x64)
    f32x4 s4[4];
    #pragma unroll
    for (int cf = 0; cf < 4; ++cf) s4[cf] = (f32x4)0.0f;
    #pragma unroll
    for (int kk = 0; kk < 2; ++kk)
      #pragma unroll
      for (int cf = 0; cf < 4; ++cf) {
        const bf16x8 bk = *(const bf16x8*)(smem + 8192 + (cf * 16 + fr) * 128 + ((kk * 64 + fb) ^ sw));
        s4[cf] = __builtin_amdgcn_mfma_f32_16x16x32_bf16(aq[kk], bk, s4[cf], 0, 0, 0);
      }
    // scale + column mask
    #pragma unroll
    for (int cf = 0; cf < 4; ++cf) {
      const int col = kb * 64 + cf * 16 + fr;
      const bool valid = col < SEQ;
      #pragma unroll
      for (int r = 0; r < 4; ++r)
        s4[cf][r] = valid ? s4[cf][r] * 0.125f : -__builtin_inff();
    }
    // online softmax
    float mt[4];
    #pragma unroll
    for (int r = 0; r < 4; ++r) {
      float m = fmaxf(fmaxf(s4[0][r], s4[1][r]), fmaxf(s4[2][r], s4[3][r]));
      #pragma unroll
      for (int off = 1; off < 16; off <<= 1) m = fmaxf(m, __shfl_xor(m, off));
      mt[r] = m;
    }
    float rsum[4];
    #pragma unroll
    for (int r = 0; r < 4; ++r) {
      const float mn = fmaxf(m_run[r], mt[r]);
      const float alpha = exp2f((m_run[r] - mn) * 1.44269504f);
      m_run[r] = mn;
      l_run[r] *= alpha;
      #pragma unroll
      for (int cf = 0; cf < 4; ++cf) acc[cf][r] *= alpha;
      float sum = 0.f;
      #pragma unroll
      for (int cf = 0; cf < 4; ++cf) {
        const float p = exp2f((s4[cf][r] - mn) * 1.44269504f);
        s4[cf][r] = p;
        sum += p;
      }
      rsum[r] = sum;
    }
    #pragma unroll
    for (int r = 0; r < 4; ++r) {
      float sum = rsum[r];
      #pragma unroll
      for (int off = 1; off < 16; off <<= 1) sum += __shfl_xor(sum, off);
      l_run[r] += sum;
    }
    // P -> per-wave LDS (bf16, swizzled), then read back in A-layout
    #pragma unroll
    for (int cf = 0; cf < 4; ++cf)
      #pragma unroll
      for (int r = 0; r < 4; ++r) {
        const int prow = (l >> 4) * 4 + r;
        const int pcolb = (cf * 16 + fr) * 2;
        *(unsigned short*)(smem + 24576 + w * 2048 + prow * 128 + (pcolb ^ ((prow & 7) << 4))) =
            f2bf(s4[cf][r]);
      }
    asm volatile("s_waitcnt lgkmcnt(0)" ::: "memory");
    bf16x8 ap[2];
    #pragma unroll
    for (int kk = 0; kk < 2; ++kk)
      ap[kk] = *(const bf16x8*)(smem + 24576 + w * 2048 + fr * 128 + ((kk * 64 + fb) ^ sw));
    #pragma unroll
    for (int kk = 0; kk < 2; ++kk)
      #pragma unroll
      for (int cf = 0; cf < 4; ++cf) {
        const bf16x8 bv = *(const bf16x8*)(smem + 16384 + (cf * 16 + fr) * 128 + ((kk * 64 + fb) ^ sw));
        acc[cf] = __builtin_amdgcn_mfma_f32_16x16x32_bf16(ap[kk], bv, acc[cf], 0, 0, 0);
      }
  }

  #pragma unroll
  for (int r = 0; r < 4; ++r) {
    const int qrow = qb * 64 + w * 16 + (l >> 4) * 4 + r;
    if (qrow < SEQ) {
      const float rcp = 1.0f / l_run[r];
      #pragma unroll
      for (int cf = 0; cf < 4; ++cf)
        out[(rowbase + qrow) * 1024 + h * 64 + cf * 16 + fr] = f2bf(acc[cf][r] * rcp);
    }
  }
}

extern "C" void kernel_launch(void* const* d_in, const int* in_sizes, int n_in,
                              void* d_out, int out_size, void* d_ws, size_t ws_size,
                              hipStream_t stream) {
  const float* x     = (const float*)d_in[0];
  const float* ln_g  = (const float*)d_in[1];
  const float* ln_b  = (const float*)d_in[2];
  const float* w_in  = (const float*)d_in[3];
  const float* b_in  = (const float*)d_in[4];
  const float* w_out = (const float*)d_in[5];
  const float* b_out = (const float*)d_in[6];

  unsigned short* z   = (unsigned short*)d_ws;           // [MPAD][1024] bf16; reused as attn_out
  unsigned short* qv  = z   + (size_t)MPAD * 1024;       // [MPAD][2048] bf16 (q | v)
  unsigned short* wqv = qv  + (size_t)MPAD * 2048;       // [2048][1024] bf16
  unsigned short* wo  = wqv + (size_t)2048 * 1024;       // [1024][1024] bf16

  ln_kernel<<<MPAD, 256, 0, stream>>>(x, ln_g, ln_b, z);
  conv_kernel<<<(W1ELEMS + W2ELEMS) / 1024, 256, 0, stream>>>(w_in, w_out, wqv, wo);
  gemm_kernel<0><<<dim3(16, 145), 256, 0, stream>>>(z, wqv, b_in, qv, 2048);
  attn_kernel<<<dim3(10, 512), 256, 0, stream>>>(qv, z);
  gemm_kernel<1><<<dim3(8, 145), 256, 0, stream>>>(z, wo, b_out, d_out, 1024);
}

// Round 2
// 383.917 us; speedup vs baseline: 1.0709x; 1.0709x over previous
//
#include <hip/hip_runtime.h>
#include <stdint.h>

typedef short bf16x8 __attribute__((ext_vector_type(8)));
typedef float f32x4 __attribute__((ext_vector_type(4)));
typedef unsigned int uint2v __attribute__((ext_vector_type(2)));
typedef unsigned short ushort4v __attribute__((ext_vector_type(4)));
typedef float float4v __attribute__((ext_vector_type(4)));

#define MROWS 18464      // 32*577
#define MPAD  18560      // 145*128
#define SEQ   577
#define CDIM  1024
#define SPAD  640
#define W1ELEMS (2048*1024)
#define W2ELEMS (1024*1024)
#define SMCOEF 0.18033688f   // 0.125 * log2(e)

__device__ __forceinline__ unsigned short f2bf(float f) {
  unsigned int u = __float_as_uint(f);
  u += 0x7fffu + ((u >> 16) & 1u);   // RNE
  return (unsigned short)(u >> 16);
}

// pack two floats to bf16 pair (round-half-up truncation): low16=bf(a), high16=bf(b)
__device__ __forceinline__ unsigned int pack_bf16(float a, float b) {
  const unsigned int ua = __float_as_uint(a) + 0x8000u;
  const unsigned int ub = __float_as_uint(b) + 0x8000u;
  return __builtin_amdgcn_perm(ub, ua, 0x07060302u);
}

__device__ __forceinline__ void load_lds16(const void* g, void* lds) {
  __builtin_amdgcn_global_load_lds(
      (const __attribute__((address_space(1))) unsigned int*)(uint64_t)(uintptr_t)g,
      (__attribute__((address_space(3))) unsigned int*)(unsigned int)(uintptr_t)lds,
      16, 0, 0);
}

// ---------------- LayerNorm: x fp32 -> z bf16; pad rows zeroed ----------------
__global__ __launch_bounds__(256) void ln_kernel(const float* __restrict__ x,
                                                 const float* __restrict__ g,
                                                 const float* __restrict__ b,
                                                 unsigned short* __restrict__ z) {
  const int row = blockIdx.x;
  const int t = threadIdx.x;
  unsigned short* zp = z + (size_t)row * CDIM + t * 4;
  if (row >= MROWS) { *(ushort4v*)zp = (ushort4v)0; return; }
  const float4v v = *(const float4v*)(x + (size_t)row * CDIM + t * 4);
  float s  = v[0] + v[1] + v[2] + v[3];
  float ss = v[0]*v[0] + v[1]*v[1] + v[2]*v[2] + v[3]*v[3];
  #pragma unroll
  for (int off = 1; off < 64; off <<= 1) { s += __shfl_xor(s, off); ss += __shfl_xor(ss, off); }
  __shared__ float rs[4], rss[4];
  const int w = t >> 6, l = t & 63;
  if (l == 0) { rs[w] = s; rss[w] = ss; }
  __syncthreads();
  s = rs[0] + rs[1] + rs[2] + rs[3];
  ss = rss[0] + rss[1] + rss[2] + rss[3];
  const float mu = s * (1.0f / CDIM);
  const float var = ss * (1.0f / CDIM) - mu * mu;
  const float rstd = rsqrtf(var + 1e-5f);
  const float4v gv = *(const float4v*)(g + t * 4);
  const float4v bv = *(const float4v*)(b + t * 4);
  ushort4v o;
  #pragma unroll
  for (int j = 0; j < 4; ++j) o[j] = f2bf((v[j] - mu) * rstd * gv[j] + bv[j]);
  *(ushort4v*)zp = o;
}

// -------- pack+convert weights: wqv[2048][1024] (rows 0..1023 = q weights,
// rows 1024..2047 = v weights = w_in rows 2048..3071), wo[1024][1024] --------
__global__ __launch_bounds__(256) void conv_kernel(const float* __restrict__ w_in,
                                                   const float* __restrict__ w_out,
                                                   unsigned short* __restrict__ wqv,
                                                   unsigned short* __restrict__ wo) {
  const int e = (blockIdx.x * 256 + threadIdx.x) * 4;
  float4v v; unsigned short* dst;
  if (e < W1ELEMS) {
    const int row = e >> 10;
    const int srow = row < 1024 ? row : row + 1024;
    v = *(const float4v*)(w_in + (size_t)srow * 1024 + (e & 1023));
    dst = wqv + e;
  } else {
    const int e2 = e - W1ELEMS;
    v = *(const float4v*)(w_out + e2);
    dst = wo + e2;
  }
  ushort4v o;
  #pragma unroll
  for (int j = 0; j < 4; ++j) o[j] = f2bf(v[j]);
  *(ushort4v*)dst = o;
}

// ---------------- GEMM: D[m][n] = sum_k A[m][k]*B[n][k] (+bias) ----------------
// A [.][1024] bf16, B [.][1024] bf16. 128x128 tile, BK=64, 4 waves.
// MODE 0: q out     — bf16, out[row*1024+col] = acc + bias[col]
// MODE 1: proj out  — fp32, row<MROWS guard,   out[row*1024+col] = acc + bias[col]
// MODE 2: v^T out   — bf16 transposed: m-dim = v-channel c, n-dim = token;
//                     out[(n*1024+c)*640 + s] = acc + bias[c]  (token -> n,s by /577)
template<int MODE>
__global__ __launch_bounds__(256) void gemm_kernel(const unsigned short* __restrict__ A,
                                                   const unsigned short* __restrict__ B,
                                                   const float* __restrict__ bias,
                                                   void* __restrict__ outp) {
  __shared__ char smem[32768];  // A tile 16KB @0, B tile 16KB @16384; row stride 128B
  const int t = threadIdx.x;
  const int w = t >> 6, l = t & 63;
  const int m0 = blockIdx.y * 128, n0 = blockIdx.x * 128;
  const int wr = w >> 1, wc = w & 1;
  const int g4 = (l >> 4) * 4;

  f32x4 acc[4][4];
  #pragma unroll
  for (int i = 0; i < 4; ++i)
    #pragma unroll
    for (int j = 0; j < 4; ++j) acc[i][j] = (f32x4)0.0f;

  const int srow = l >> 3;
  const int scol = ((((l & 7) * 16) ^ ((srow & 7) << 4)) >> 1);    // pre-swizzled fetch col (elems)
  const int fr = l & 15;
  const int fb = (l >> 4) * 16;
  const int sw = (l & 7) << 4;                                     // == (fr&7)<<4

  for (int kb = 0; kb < 16; ++kb) {
    __syncthreads();
    const int k0 = kb * 64;
    #pragma unroll
    for (int c = 0; c < 4; ++c) {
      const int ra = w * 32 + c * 8;
      load_lds16(A + (size_t)(m0 + ra + srow) * 1024 + k0 + scol, smem + ra * 128);
      load_lds16(B + (size_t)(n0 + ra + srow) * 1024 + k0 + scol, smem + 16384 + ra * 128);
    }
    __syncthreads();
    #pragma unroll
    for (int kk = 0; kk < 2; ++kk) {
      bf16x8 af[4], bf[4];
      #pragma unroll
      for (int i = 0; i < 4; ++i)
        af[i] = *(const bf16x8*)(smem + (wr * 64 + i * 16 + fr) * 128 + ((kk * 64 + fb) ^ sw));
      #pragma unroll
      for (int j = 0; j < 4; ++j)
        bf[j] = *(const bf16x8*)(smem + 16384 + (wc * 64 + j * 16 + fr) * 128 + ((kk * 64 + fb) ^ sw));
      #pragma unroll
      for (int i = 0; i < 4; ++i)
        #pragma unroll
        for (int j = 0; j < 4; ++j)
          acc[i][j] = __builtin_amdgcn_mfma_f32_16x16x32_bf16(af[i], bf[j], acc[i][j], 0, 0, 0);
    }
  }

  if constexpr (MODE == 2) {
    unsigned short* o = (unsigned short*)outp;
    float bc[4][4];
    #pragma unroll
    for (int i = 0; i < 4; ++i)
      #pragma unroll
      for (int r = 0; r < 4; ++r) bc[i][r] = bias[m0 + wr * 64 + i * 16 + g4 + r];
    #pragma unroll
    for (int j = 0; j < 4; ++j) {
      const int token = n0 + wc * 64 + j * 16 + fr;
      const unsigned int nimg = (unsigned int)(((unsigned long long)(unsigned int)token * 7443757ull) >> 32);
      const int s = token - (int)(nimg * 577u);
      const size_t bj = (size_t)nimg * (1024u * SPAD) + (unsigned int)s;
      if (token < MROWS) {
        #pragma unroll
        for (int i = 0; i < 4; ++i)
          #pragma unroll
          for (int r = 0; r < 4; ++r) {
            const int c = m0 + wr * 64 + i * 16 + g4 + r;
            o[bj + (size_t)c * SPAD] = f2bf(acc[i][j][r] + bc[i][r]);
          }
      }
    }
  } else {
    #pragma unroll
    for (int i = 0; i < 4; ++i) {
      #pragma unroll
      for (int j = 0; j < 4; ++j) {
        const int col = n0 + wc * 64 + j * 16 + fr;
        const float bv = bias[col];
        #pragma unroll
        for (int r = 0; r < 4; ++r) {
          const int row = m0 + wr * 64 + i * 16 + g4 + r;
          const float val = acc[i][j][r] + bv;
          if (MODE == 0) {
            ((unsigned short*)outp)[(size_t)row * 1024 + col] = f2bf(val);
          } else {
            if (row < MROWS) ((float*)outp)[(size_t)row * 1024 + col] = val;
          }
        }
      }
    }
  }
}

// ---------------- flash attention, k = q ('qq'), swapped-QK layout ----------------
// grid (10, 512): x = 64-row q-block, y = (n,h). 4 waves, each owns 16 q-rows.
// S^T = mfma(K_frag, Q_frag): lane holds 16 scores of q-row (l&15).
__global__ __launch_bounds__(256) void attn_kernel(const unsigned short* __restrict__ qbuf,
                                                   const unsigned short* __restrict__ vt,
                                                   unsigned short* __restrict__ out) {
  __shared__ char smem[24576];  // K tile 8KB @0, V^T tile 8KB @8192, P 4x2KB @16384
  const int t = threadIdx.x, w = t >> 6, l = t & 63;
  const int g = l >> 4, fr = l & 15;
  const int qb = blockIdx.x, nh = blockIdx.y;
  const int n = nh >> 4, h = nh & 15;
  const size_t rowbase = (size_t)n * SEQ;
  const int sw = (l & 7) << 4;

  // Q B-fragment from global (held all kernel): lane -> q-row (l&15), d = g*8 + kk*32 ..
  bf16x8 bq[2];
  {
    const unsigned short* qp = qbuf + (rowbase + qb * 64 + w * 16 + fr) * 1024 + h * 64 + g * 8;
    bq[0] = *(const bf16x8*)qp;
    bq[1] = *(const bf16x8*)(qp + 32);
  }

  const int srow = l >> 3;
  const int scolE = ((((l & 7) * 16) ^ ((srow & 7) << 4)) >> 1);
  const unsigned short* ksrc = qbuf + (rowbase + w * 16 + srow) * 1024 + h * 64 + scolE;
  const unsigned short* vsrc = vt + ((size_t)nh * 64 + w * 16 + srow) * SPAD + scolE;
  char* kdst = smem + (w * 16) * 128;
  char* vdst = smem + 8192 + (w * 16) * 128;
  char* pw = smem + 16384 + w * 2048 + fr * 128;
  const char* pr = smem + 16384 + w * 2048 + fr * 128;

  f32x4 acc[4];
  #pragma unroll
  for (int cf = 0; cf < 4; ++cf) acc[cf] = (f32x4)0.0f;
  float m_run = -__builtin_inff(), l_run = 0.0f, mc = 0.0f;

  for (int kb = 0; kb < 10; ++kb) {
    __syncthreads();
    load_lds16(ksrc + (size_t)(kb * 64) * 1024, kdst);
    load_lds16(ksrc + (size_t)(kb * 64 + 8) * 1024, kdst + 1024);
    load_lds16(vsrc + kb * 64, vdst);
    load_lds16(vsrc + 8 * SPAD + kb * 64, vdst + 1024);
    __syncthreads();

    // S^T[s_local][q]: s_local = g*4 + r + 16*cf, q = l&15
    f32x4 s4[4];
    #pragma unroll
    for (int cf = 0; cf < 4; ++cf) s4[cf] = (f32x4)0.0f;
    #pragma unroll
    for (int kk = 0; kk < 2; ++kk)
      #pragma unroll
      for (int cf = 0; cf < 4; ++cf) {
        const bf16x8 af = *(const bf16x8*)(smem + (cf * 16 + fr) * 128 + ((kk * 64 + g * 16) ^ sw));
        s4[cf] = __builtin_amdgcn_mfma_f32_16x16x32_bf16(af, bq[kk], s4[cf], 0, 0, 0);
      }

    if (kb == 9) {  // 577 = 9*64 + 1: only s_local == 0 valid
      #pragma unroll
      for (int cf = 0; cf < 4; ++cf)
        #pragma unroll
        for (int r = 0; r < 4; ++r)
          if (cf != 0 || r != 0) s4[cf][r] = -__builtin_inff();
      s4[0][0] = (g == 0) ? s4[0][0] : -__builtin_inff();
    }

    // row max (in-lane 16 + cross-group)
    float mx = s4[0][0];
    #pragma unroll
    for (int cf = 0; cf < 4; ++cf)
      #pragma unroll
      for (int r = 0; r < 4; ++r)
        if (cf || r) mx = fmaxf(mx, s4[cf][r]);
    mx = fmaxf(mx, __shfl_xor(mx, 16));
    mx = fmaxf(mx, __shfl_xor(mx, 32));

    if (__any(mx > m_run)) {
      const float mn = fmaxf(m_run, mx);
      const float al = exp2f((m_run - mn) * SMCOEF);
      m_run = mn; mc = mn * SMCOEF;
      l_run *= al;
      #pragma unroll
      for (int r = 0; r < 4; ++r) {
        const float ar = __shfl(al, g * 4 + r);
        #pragma unroll
        for (int cf = 0; cf < 4; ++cf) acc[cf][r] *= ar;
      }
    }

    float sum = 0.0f;
    #pragma unroll
    for (int cf = 0; cf < 4; ++cf)
      #pragma unroll
      for (int r = 0; r < 4; ++r) {
        const float p = exp2f(fmaf(s4[cf][r], SMCOEF, -mc));
        s4[cf][r] = p;
        sum += p;
      }
    sum += __shfl_xor(sum, 16);
    sum += __shfl_xor(sum, 32);
    l_run += sum;

    // P[q][s] per-wave LDS: row q=fr (128B), packed b64 writes
    #pragma unroll
    for (int cf = 0; cf < 4; ++cf) {
      uint2v u;
      u[0] = pack_bf16(s4[cf][0], s4[cf][1]);
      u[1] = pack_bf16(s4[cf][2], s4[cf][3]);
      *(uint2v*)(pw + ((g * 8 + cf * 32) ^ sw)) = u;
    }
    asm volatile("s_waitcnt lgkmcnt(0)" ::: "memory");
    bf16x8 ap[2];
    #pragma unroll
    for (int kk = 0; kk < 2; ++kk)
      ap[kk] = *(const bf16x8*)(pr + ((g * 16 + kk * 64) ^ sw));
    #pragma unroll
    for (int kk = 0; kk < 2; ++kk)
      #pragma unroll
      for (int cf = 0; cf < 4; ++cf) {
        const bf16x8 bv = *(const bf16x8*)(smem + 8192 + (cf * 16 + fr) * 128 + ((kk * 64 + g * 16) ^ sw));
        acc[cf] = __builtin_amdgcn_mfma_f32_16x16x32_bf16(ap[kk], bv, acc[cf], 0, 0, 0);
      }
  }

  const float rcp = 1.0f / l_run;
  #pragma unroll
  for (int r = 0; r < 4; ++r) {
    const float rr = __shfl(rcp, g * 4 + r);
    const int qg = qb * 64 + w * 16 + g * 4 + r;
    if (qg < SEQ) {
      #pragma unroll
      for (int cf = 0; cf < 4; ++cf)
        out[(rowbase + qg) * 1024 + h * 64 + cf * 16 + fr] = f2bf(acc[cf][r] * rr);
    }
  }
}

extern "C" void kernel_launch(void* const* d_in, const int* in_sizes, int n_in,
                              void* d_out, int out_size, void* d_ws, size_t ws_size,
                              hipStream_t stream) {
  const float* x     = (const float*)d_in[0];
  const float* ln_g  = (const float*)d_in[1];
  const float* ln_b  = (const float*)d_in[2];
  const float* w_in  = (const float*)d_in[3];
  const float* b_in  = (const float*)d_in[4];
  const float* w_out = (const float*)d_in[5];
  const float* b_out = (const float*)d_in[6];

  unsigned short* z    = (unsigned short*)d_ws;            // [MPAD][1024] bf16; reused as attn_out
  unsigned short* qbuf = z + (size_t)MPAD * 1024;          // [MPAD][1024] bf16 (q, == k)
  unsigned short* vt   = qbuf + (size_t)MPAD * 1024;       // [512*64][640] bf16 (V^T per (n,h))
  unsigned short* wqv  = vt + (size_t)512 * 64 * SPAD;     // [2048][1024] bf16
  unsigned short* wo   = wqv + (size_t)2048 * 1024;        // [1024][1024] bf16

  hipMemsetAsync(vt, 0, (size_t)512 * 64 * SPAD * 2, stream);  // pad region must be finite
  ln_kernel<<<MPAD, 256, 0, stream>>>(x, ln_g, ln_b, z);
  conv_kernel<<<(W1ELEMS + W2ELEMS) / 1024, 256, 0, stream>>>(w_in, w_out, wqv, wo);
  gemm_kernel<0><<<dim3(8, 145), 256, 0, stream>>>(z, wqv, b_in, qbuf);
  gemm_kernel<2><<<dim3(145, 8), 256, 0, stream>>>(wqv + (size_t)1024 * 1024, z, b_in + 2048, vt);
  attn_kernel<<<dim3(10, 512), 256, 0, stream>>>(qbuf, vt, z);
  gemm_kernel<1><<<dim3(8, 145), 256, 0, stream>>>(z, wo, b_out, d_out);
}

// Round 4
// 314.255 us; speedup vs baseline: 1.3083x; 1.2217x over previous
//
#include <hip/hip_runtime.h>
#include <stdint.h>

typedef short bf16x8 __attribute__((ext_vector_type(8)));
typedef float f32x4 __attribute__((ext_vector_type(4)));
typedef unsigned int uint4v __attribute__((ext_vector_type(4)));
typedef unsigned short ushort4v __attribute__((ext_vector_type(4)));
typedef float float4v __attribute__((ext_vector_type(4)));

#define MROWS 18464      // 32*577
#define MPAD  18560      // 145*128
#define SEQ   577
#define CDIM  1024
#define SPAD  640
#define W1ELEMS (2048*1024)
#define W2ELEMS (1024*1024)
#define SQC 0.42466089f   // sqrt(0.125 * log2(e)); applied to q AND k (same buffer)

__device__ __forceinline__ unsigned short f2bf(float f) {
  unsigned int u = __float_as_uint(f);
  u += 0x7fffu + ((u >> 16) & 1u);   // RNE
  return (unsigned short)(u >> 16);
}

__device__ __forceinline__ void load_lds16(const void* g, void* lds) {
  __builtin_amdgcn_global_load_lds(
      (const __attribute__((address_space(1))) unsigned int*)(uint64_t)(uintptr_t)g,
      (__attribute__((address_space(3))) unsigned int*)(unsigned int)(uintptr_t)lds,
      16, 0, 0);
}

// ---------------- LayerNorm: x fp32 -> z bf16; pad rows zeroed ----------------
__global__ __launch_bounds__(256) void ln_kernel(const float* __restrict__ x,
                                                 const float* __restrict__ g,
                                                 const float* __restrict__ b,
                                                 unsigned short* __restrict__ z) {
  const int row = blockIdx.x;
  const int t = threadIdx.x;
  unsigned short* zp = z + (size_t)row * CDIM + t * 4;
  if (row >= MROWS) { *(ushort4v*)zp = (ushort4v)0; return; }
  const float4v v = *(const float4v*)(x + (size_t)row * CDIM + t * 4);
  float s  = v[0] + v[1] + v[2] + v[3];
  float ss = v[0]*v[0] + v[1]*v[1] + v[2]*v[2] + v[3]*v[3];
  #pragma unroll
  for (int off = 1; off < 64; off <<= 1) { s += __shfl_xor(s, off); ss += __shfl_xor(ss, off); }
  __shared__ float rs[4], rss[4];
  const int w = t >> 6, l = t & 63;
  if (l == 0) { rs[w] = s; rss[w] = ss; }
  __syncthreads();
  s = rs[0] + rs[1] + rs[2] + rs[3];
  ss = rss[0] + rss[1] + rss[2] + rss[3];
  const float mu = s * (1.0f / CDIM);
  const float var = ss * (1.0f / CDIM) - mu * mu;
  const float rstd = rsqrtf(var + 1e-5f);
  const float4v gv = *(const float4v*)(g + t * 4);
  const float4v bv = *(const float4v*)(b + t * 4);
  ushort4v o;
  #pragma unroll
  for (int j = 0; j < 4; ++j) o[j] = f2bf((v[j] - mu) * rstd * gv[j] + bv[j]);
  *(ushort4v*)zp = o;
}

// -------- pack+convert weights --------
__global__ __launch_bounds__(256) void conv_kernel(const float* __restrict__ w_in,
                                                   const float* __restrict__ w_out,
                                                   unsigned short* __restrict__ wqv,
                                                   unsigned short* __restrict__ wo) {
  const int e = (blockIdx.x * 256 + threadIdx.x) * 4;
  float4v v; unsigned short* dst;
  if (e < W1ELEMS) {
    const int row = e >> 10;
    const int srow = row < 1024 ? row : row + 1024;
    v = *(const float4v*)(w_in + (size_t)srow * 1024 + (e & 1023));
    dst = wqv + e;
  } else {
    const int e2 = e - W1ELEMS;
    v = *(const float4v*)(w_out + e2);
    dst = wo + e2;
  }
  ushort4v o;
  #pragma unroll
  for (int j = 0; j < 4; ++j) o[j] = f2bf(v[j]);
  *(ushort4v*)dst = o;
}

// ---------------- GEMM: D[m][n] = sum_k A[m][k]*B[n][k] (+bias) ----------------
// MODE 0: q out, bf16 [MPAD][1024], scaled by SQC.
// MODE 1: proj out, fp32, row<MROWS guard.
// MODE 2: v^T out, bf16: m = channel, n = token; vt[(img*1024+c)*640 + s].
template<int MODE>
__global__ __launch_bounds__(256) void gemm_kernel(const unsigned short* __restrict__ A,
                                                   const unsigned short* __restrict__ B,
                                                   const float* __restrict__ bias,
                                                   void* __restrict__ outp) {
  __shared__ char smem[34816];  // main loop: A tile @0 (16KB), B tile @16384 (16KB)
  const int t = threadIdx.x;
  const int w = t >> 6, l = t & 63;
  const int m0 = blockIdx.y * 128, n0 = blockIdx.x * 128;
  const int wr = w >> 1, wc = w & 1;
  const int g4 = (l >> 4) * 4;

  f32x4 acc[4][4];
  #pragma unroll
  for (int i = 0; i < 4; ++i)
    #pragma unroll
    for (int j = 0; j < 4; ++j) acc[i][j] = (f32x4)0.0f;

  const int srow = l >> 3;
  const int scol = ((((l & 7) * 16) ^ ((srow & 7) << 4)) >> 1);
  const int fr = l & 15;
  const int fb = (l >> 4) * 16;
  const int sw = (l & 7) << 4;

  for (int kb = 0; kb < 16; ++kb) {
    __syncthreads();
    const int k0 = kb * 64;
    #pragma unroll
    for (int c = 0; c < 4; ++c) {
      const int ra = w * 32 + c * 8;
      load_lds16(A + (size_t)(m0 + ra + srow) * 1024 + k0 + scol, smem + ra * 128);
      load_lds16(B + (size_t)(n0 + ra + srow) * 1024 + k0 + scol, smem + 16384 + ra * 128);
    }
    __syncthreads();
    #pragma unroll
    for (int kk = 0; kk < 2; ++kk) {
      bf16x8 af[4], bf[4];
      #pragma unroll
      for (int i = 0; i < 4; ++i)
        af[i] = *(const bf16x8*)(smem + (wr * 64 + i * 16 + fr) * 128 + ((kk * 64 + fb) ^ sw));
      #pragma unroll
      for (int j = 0; j < 4; ++j)
        bf[j] = *(const bf16x8*)(smem + 16384 + (wc * 64 + j * 16 + fr) * 128 + ((kk * 64 + fb) ^ sw));
      #pragma unroll
      for (int i = 0; i < 4; ++i)
        #pragma unroll
        for (int j = 0; j < 4; ++j)
          acc[i][j] = __builtin_amdgcn_mfma_f32_16x16x32_bf16(af[i], bf[j], acc[i][j], 0, 0, 0);
    }
  }

  __syncthreads();  // all LDS tile reads done before epilogue reuse

  if constexpr (MODE == 0) {
    unsigned short* sm = (unsigned short*)smem;   // [128][136]
    float bcol[4];
    #pragma unroll
    for (int j = 0; j < 4; ++j) bcol[j] = bias[n0 + wc * 64 + j * 16 + fr];
    #pragma unroll
    for (int i = 0; i < 4; ++i)
      #pragma unroll
      for (int j = 0; j < 4; ++j)
        #pragma unroll
        for (int r = 0; r < 4; ++r)
          sm[(wr * 64 + i * 16 + g4 + r) * 136 + wc * 64 + j * 16 + fr] =
              f2bf((acc[i][j][r] + bcol[j]) * SQC);
    __syncthreads();
    unsigned short* o = (unsigned short*)outp;
    #pragma unroll
    for (int it = 0; it < 8; ++it) {
      const int cid = it * 256 + t;
      const int row = cid >> 4, ch = cid & 15;
      *(uint4v*)(o + (size_t)(m0 + row) * 1024 + n0 + ch * 8) =
          *(const uint4v*)(sm + row * 136 + ch * 8);
    }
  } else if constexpr (MODE == 1) {
    float* smf = (float*)smem;                    // [64][132]
    float bcol[4];
    #pragma unroll
    for (int j = 0; j < 4; ++j) bcol[j] = bias[n0 + wc * 64 + j * 16 + fr];
    float* o = (float*)outp;
    for (int half = 0; half < 2; ++half) {
      if (wr == half) {
        #pragma unroll
        for (int i = 0; i < 4; ++i)
          #pragma unroll
          for (int j = 0; j < 4; ++j)
            #pragma unroll
            for (int r = 0; r < 4; ++r)
              smf[(i * 16 + g4 + r) * 132 + wc * 64 + j * 16 + fr] = acc[i][j][r] + bcol[j];
      }
      __syncthreads();
      #pragma unroll
      for (int it = 0; it < 8; ++it) {
        const int cid = it * 256 + t;
        const int row = cid >> 5, ch = cid & 31;
        const int grow = m0 + half * 64 + row;
        if (grow < MROWS)
          *(float4v*)(o + (size_t)grow * 1024 + n0 + ch * 4) =
              *(const float4v*)(smf + row * 132 + ch * 4);
      }
      __syncthreads();
    }
  } else {  // MODE 2: rows = channels, cols = tokens; store channel-major into vt
    unsigned short* sm = (unsigned short*)smem;   // [128][136]
    float brow[4][4];
    #pragma unroll
    for (int i = 0; i < 4; ++i)
      #pragma unroll
      for (int r = 0; r < 4; ++r) brow[i][r] = bias[m0 + wr * 64 + i * 16 + g4 + r];
    #pragma unroll
    for (int i = 0; i < 4; ++i)
      #pragma unroll
      for (int j = 0; j < 4; ++j)
        #pragma unroll
        for (int r = 0; r < 4; ++r)
          sm[(wr * 64 + i * 16 + g4 + r) * 136 + wc * 64 + j * 16 + fr] =
              f2bf(acc[i][j][r] + brow[i][r]);
    __syncthreads();
    unsigned short* o = (unsigned short*)outp;
    const int col = t & 127;
    const int token = n0 + col;
    const int rbase = t >> 7;   // 0 or 1
    if (token < MROWS) {
      const unsigned int nimg = (unsigned int)token / 577u;
      const int s = token - (int)(nimg * 577u);
      unsigned short* op = o + ((size_t)nimg * 1024 + m0 + rbase) * SPAD + s;
      const unsigned short* sp = sm + rbase * 136 + col;
      #pragma unroll 8
      for (int it = 0; it < 64; ++it)
        op[(size_t)it * 2 * SPAD] = sp[it * 2 * 136];
    }
  }
}

// ---------------- flash attention, k = q ('qq'), no-max softmax ----------------
// 1-D grid 5120, XCD-chunked: bid&7 -> XCD, nh-major so the 10 qb-blocks of one
// nh are temporally adjacent on one XCD (K/V L2-resident).
__global__ __launch_bounds__(256) void attn_kernel(const unsigned short* __restrict__ qbuf,
                                                   const unsigned short* __restrict__ vt,
                                                   unsigned short* __restrict__ out) {
  __shared__ char smem[16384];  // K tile 8KB @0, V^T tile 8KB @8192
  const int t = threadIdx.x, w = t >> 6, l = t & 63;
  const int g = l >> 4, fr = l & 15;
  const int bid = blockIdx.x;
  const int xcd = bid & 7, idx = bid >> 3;
  const int nhl = idx / 10;
  const int qb = idx - nhl * 10;
  const int nh = xcd * 64 + nhl;
  const int n = nh >> 4, h = nh & 15;
  const size_t rowbase = (size_t)n * SEQ;
  const int sw = (l & 7) << 4;

  // Q B-fragment (pre-scaled by SQC in GEMM0): lane -> q-row fr, k = g*8 + kk*32 + e
  bf16x8 bq[2];
  {
    const unsigned short* qp = qbuf + (rowbase + qb * 64 + w * 16 + fr) * 1024 + h * 64 + g * 8;
    bq[0] = *(const bf16x8*)qp;
    bq[1] = *(const bf16x8*)(qp + 32);
  }

  const int srow = l >> 3;
  const int scolE = ((((l & 7) * 16) ^ ((srow & 7) << 4)) >> 1);
  const unsigned short* ksrc = qbuf + (rowbase + w * 16 + srow) * 1024 + h * 64 + scolE;
  const unsigned short* vsrc = vt + ((size_t)nh * 64 + w * 16 + srow) * SPAD + scolE;
  char* kdst = smem + (w * 16) * 128;
  char* vdst = smem + 8192 + (w * 16) * 128;

  f32x4 acc[4];
  #pragma unroll
  for (int cf = 0; cf < 4; ++cf) acc[cf] = (f32x4)0.0f;
  float l_run = 0.0f;

  for (int kb = 0; kb < 10; ++kb) {
    __syncthreads();
    load_lds16(ksrc + (size_t)(kb * 64) * 1024, kdst);
    load_lds16(ksrc + (size_t)(kb * 64 + 8) * 1024, kdst + 1024);
    load_lds16(vsrc + kb * 64, vdst);
    load_lds16(vsrc + 8 * SPAD + kb * 64, vdst + 1024);
    __syncthreads();

    // S^T[s_local][q]: s_local = cf*16 + g*4 + r, q = fr (already ×0.125·log2e folded)
    f32x4 s4[4];
    #pragma unroll
    for (int cf = 0; cf < 4; ++cf) s4[cf] = (f32x4)0.0f;
    #pragma unroll
    for (int kk = 0; kk < 2; ++kk)
      #pragma unroll
      for (int cf = 0; cf < 4; ++cf) {
        const bf16x8 af = *(const bf16x8*)(smem + (cf * 16 + fr) * 128 + ((kk * 64 + g * 16) ^ sw));
        s4[cf] = __builtin_amdgcn_mfma_f32_16x16x32_bf16(af, bq[kk], s4[cf], 0, 0, 0);
      }

    if (kb == 9) {  // 577 = 9*64 + 1: only s_local == 0 valid
      #pragma unroll
      for (int cf = 0; cf < 4; ++cf)
        #pragma unroll
        for (int r = 0; r < 4; ++r)
          if (cf != 0 || r != 0) s4[cf][r] = -__builtin_inff();
      s4[0][0] = (g == 0) ? s4[0][0] : -__builtin_inff();
    }

    // p = exp2(s), row-sum (no max subtraction: inputs bounded, f32-safe)
    float sum = 0.0f;
    #pragma unroll
    for (int cf = 0; cf < 4; ++cf)
      #pragma unroll
      for (int r = 0; r < 4; ++r) {
        const float p = __builtin_amdgcn_exp2f(s4[cf][r]);
        s4[cf][r] = p;
        sum += p;
      }
    sum += __shfl_xor(sum, 16);
    sum += __shfl_xor(sum, 32);
    l_run += sum;

    // pack to bf16 pairs: pka[cf] = (r0,r1), pkb[cf] = (r2,r3)
    unsigned int pka[4], pkb[4];
    #pragma unroll
    for (int cf = 0; cf < 4; ++cf) {
      asm("v_cvt_pk_bf16_f32 %0, %1, %2" : "=v"(pka[cf]) : "v"(s4[cf][0]), "v"(s4[cf][1]));
      asm("v_cvt_pk_bf16_f32 %0, %1, %2" : "=v"(pkb[cf]) : "v"(s4[cf][2]), "v"(s4[cf][3]));
    }

    // P^T -> PV A-fragment via permlane32_swap + permlane16_swap (T12).
    // For A = pk?[2kk], B = pk?[2kk+1]:
    //   swap32: A1=[A0:31,B0:31], B1=[A32:63,B32:63]
    //   swap16: T0=[A0:15,A32:47,B0:15,B32:47] (ap dword from src lanes (g&1)*32+fr)
    //           T2=[A16:31,A48:63,B16:31,B48:63] (src lanes (g&1)*32+16+fr)
    bf16x8 ap[2];
    #pragma unroll
    for (int kk = 0; kk < 2; ++kk) {
      unsigned int a0 = pka[2 * kk], b0 = pka[2 * kk + 1];
      unsigned int a1 = pkb[2 * kk], b1 = pkb[2 * kk + 1];
      asm("v_permlane32_swap_b32 %0, %1" : "+v"(a0), "+v"(b0));
      asm("v_permlane16_swap_b32 %0, %1" : "+v"(a0), "+v"(b0));
      asm("v_permlane32_swap_b32 %0, %1" : "+v"(a1), "+v"(b1));
      asm("v_permlane16_swap_b32 %0, %1" : "+v"(a1), "+v"(b1));
      union { unsigned int i[4]; bf16x8 v; } u;
      u.i[0] = a0;  // e0,e1: pka from lane (g&1)*32+fr
      u.i[1] = a1;  // e2,e3: pkb from lane (g&1)*32+fr
      u.i[2] = b0;  // e4,e5: pka from lane (g&1)*32+16+fr
      u.i[3] = b1;  // e6,e7: pkb from lane (g&1)*32+16+fr
      ap[kk] = u.v;
    }

    #pragma unroll
    for (int kk = 0; kk < 2; ++kk)
      #pragma unroll
      for (int cf = 0; cf < 4; ++cf) {
        const bf16x8 bv = *(const bf16x8*)(smem + 8192 + (cf * 16 + fr) * 128 + ((kk * 64 + g * 16) ^ sw));
        acc[cf] = __builtin_amdgcn_mfma_f32_16x16x32_bf16(ap[kk], bv, acc[cf], 0, 0, 0);
      }
  }

  const float rcp = 1.0f / l_run;
  #pragma unroll
  for (int r = 0; r < 4; ++r) {
    const float rr = __shfl(rcp, g * 4 + r);
    const int qg = qb * 64 + w * 16 + g * 4 + r;
    if (qg < SEQ) {
      #pragma unroll
      for (int cf = 0; cf < 4; ++cf)
        out[(rowbase + qg) * 1024 + h * 64 + cf * 16 + fr] = f2bf(acc[cf][r] * rr);
    }
  }
}

extern "C" void kernel_launch(void* const* d_in, const int* in_sizes, int n_in,
                              void* d_out, int out_size, void* d_ws, size_t ws_size,
                              hipStream_t stream) {
  const float* x     = (const float*)d_in[0];
  const float* ln_g  = (const float*)d_in[1];
  const float* ln_b  = (const float*)d_in[2];
  const float* w_in  = (const float*)d_in[3];
  const float* b_in  = (const float*)d_in[4];
  const float* w_out = (const float*)d_in[5];
  const float* b_out = (const float*)d_in[6];

  unsigned short* z    = (unsigned short*)d_ws;            // [MPAD][1024] bf16; reused as attn_out
  unsigned short* qbuf = z + (size_t)MPAD * 1024;          // [MPAD][1024] bf16 (q = k, pre-scaled)
  unsigned short* vt   = qbuf + (size_t)MPAD * 1024;       // [32*1024][640] bf16 (V^T)
  unsigned short* wqv  = vt + (size_t)512 * 64 * SPAD;     // [2048][1024] bf16
  unsigned short* wo   = wqv + (size_t)2048 * 1024;        // [1024][1024] bf16

  hipMemsetAsync(vt, 0, (size_t)512 * 64 * SPAD * 2, stream);  // pad cols must be finite (NaN*0 hazard)
  ln_kernel<<<MPAD, 256, 0, stream>>>(x, ln_g, ln_b, z);
  conv_kernel<<<(W1ELEMS + W2ELEMS) / 1024, 256, 0, stream>>>(w_in, w_out, wqv, wo);
  gemm_kernel<0><<<dim3(8, 145), 256, 0, stream>>>(z, wqv, b_in, qbuf);
  gemm_kernel<2><<<dim3(145, 8), 256, 0, stream>>>(wqv + (size_t)1024 * 1024, z, b_in + 2048, vt);
  attn_kernel<<<5120, 256, 0, stream>>>(qbuf, vt, z);
  gemm_kernel<1><<<dim3(8, 145), 256, 0, stream>>>(z, wo, b_out, d_out);
}

// Round 5
// 310.967 us; speedup vs baseline: 1.3221x; 1.0106x over previous
//
#include <hip/hip_runtime.h>
#include <stdint.h>

typedef short bf16x8 __attribute__((ext_vector_type(8)));
typedef float f32x4 __attribute__((ext_vector_type(4)));
typedef unsigned int uint4v __attribute__((ext_vector_type(4)));
typedef unsigned short ushort4v __attribute__((ext_vector_type(4)));
typedef float float4v __attribute__((ext_vector_type(4)));

#define MROWS 18464      // 32*577
#define MPAD  18560      // 145*128
#define SEQ   577
#define CDIM  1024
#define SPAD  640
#define W1ELEMS (2048*1024)
#define W2ELEMS (1024*1024)
#define SQC 0.42466089f   // sqrt(0.125 * log2(e)); applied to q AND k (same buffer)

__device__ __forceinline__ unsigned short f2bf(float f) {
  unsigned int u = __float_as_uint(f);
  u += 0x7fffu + ((u >> 16) & 1u);   // RNE
  return (unsigned short)(u >> 16);
}

__device__ __forceinline__ void load_lds16(const void* g, void* lds) {
  __builtin_amdgcn_global_load_lds(
      (const __attribute__((address_space(1))) unsigned int*)(uint64_t)(uintptr_t)g,
      (__attribute__((address_space(3))) unsigned int*)(unsigned int)(uintptr_t)lds,
      16, 0, 0);
}

// ---------------- LayerNorm: x fp32 -> z bf16; pad rows zeroed ----------------
__global__ __launch_bounds__(256) void ln_kernel(const float* __restrict__ x,
                                                 const float* __restrict__ g,
                                                 const float* __restrict__ b,
                                                 unsigned short* __restrict__ z) {
  const int row = blockIdx.x;
  const int t = threadIdx.x;
  unsigned short* zp = z + (size_t)row * CDIM + t * 4;
  if (row >= MROWS) { *(ushort4v*)zp = (ushort4v)0; return; }
  const float4v v = *(const float4v*)(x + (size_t)row * CDIM + t * 4);
  float s  = v[0] + v[1] + v[2] + v[3];
  float ss = v[0]*v[0] + v[1]*v[1] + v[2]*v[2] + v[3]*v[3];
  #pragma unroll
  for (int off = 1; off < 64; off <<= 1) { s += __shfl_xor(s, off); ss += __shfl_xor(ss, off); }
  __shared__ float rs[4], rss[4];
  const int w = t >> 6, l = t & 63;
  if (l == 0) { rs[w] = s; rss[w] = ss; }
  __syncthreads();
  s = rs[0] + rs[1] + rs[2] + rs[3];
  ss = rss[0] + rss[1] + rss[2] + rss[3];
  const float mu = s * (1.0f / CDIM);
  const float var = ss * (1.0f / CDIM) - mu * mu;
  const float rstd = rsqrtf(var + 1e-5f);
  const float4v gv = *(const float4v*)(g + t * 4);
  const float4v bv = *(const float4v*)(b + t * 4);
  ushort4v o;
  #pragma unroll
  for (int j = 0; j < 4; ++j) o[j] = f2bf((v[j] - mu) * rstd * gv[j] + bv[j]);
  *(ushort4v*)zp = o;
}

// -------- pack+convert weights --------
__global__ __launch_bounds__(256) void conv_kernel(const float* __restrict__ w_in,
                                                   const float* __restrict__ w_out,
                                                   unsigned short* __restrict__ wqv,
                                                   unsigned short* __restrict__ wo) {
  const int e = (blockIdx.x * 256 + threadIdx.x) * 4;
  float4v v; unsigned short* dst;
  if (e < W1ELEMS) {
    const int row = e >> 10;
    const int srow = row < 1024 ? row : row + 1024;
    v = *(const float4v*)(w_in + (size_t)srow * 1024 + (e & 1023));
    dst = wqv + e;
  } else {
    const int e2 = e - W1ELEMS;
    v = *(const float4v*)(w_out + e2);
    dst = wo + e2;
  }
  ushort4v o;
  #pragma unroll
  for (int j = 0; j < 4; ++j) o[j] = f2bf(v[j]);
  *(ushort4v*)dst = o;
}

// ---------------- GEMM: D[m][n] = sum_k A[m][k]*B[n][k] (+bias) ----------------
// MODE 0: q out, bf16 [MPAD][1024], scaled by SQC.
// MODE 1: proj out, fp32, row<MROWS guard.
// MODE 2: v^T out, bf16: m = channel, n = token; vt[(img*1024+c)*640 + s].
template<int MODE>
__global__ __launch_bounds__(256) void gemm_kernel(const unsigned short* __restrict__ A,
                                                   const unsigned short* __restrict__ B,
                                                   const float* __restrict__ bias,
                                                   void* __restrict__ outp) {
  __shared__ char smem[34816];  // main loop: A tile @0 (16KB), B tile @16384 (16KB)
  const int t = threadIdx.x;
  const int w = t >> 6, l = t & 63;
  const int m0 = blockIdx.y * 128, n0 = blockIdx.x * 128;
  const int wr = w >> 1, wc = w & 1;
  const int g4 = (l >> 4) * 4;

  f32x4 acc[4][4];
  #pragma unroll
  for (int i = 0; i < 4; ++i)
    #pragma unroll
    for (int j = 0; j < 4; ++j) acc[i][j] = (f32x4)0.0f;

  const int srow = l >> 3;
  const int scol = ((((l & 7) * 16) ^ ((srow & 7) << 4)) >> 1);
  const int fr = l & 15;
  const int fb = (l >> 4) * 16;
  const int sw = (l & 7) << 4;

  for (int kb = 0; kb < 16; ++kb) {
    __syncthreads();
    const int k0 = kb * 64;
    #pragma unroll
    for (int c = 0; c < 4; ++c) {
      const int ra = w * 32 + c * 8;
      load_lds16(A + (size_t)(m0 + ra + srow) * 1024 + k0 + scol, smem + ra * 128);
      load_lds16(B + (size_t)(n0 + ra + srow) * 1024 + k0 + scol, smem + 16384 + ra * 128);
    }
    __syncthreads();
    #pragma unroll
    for (int kk = 0; kk < 2; ++kk) {
      bf16x8 af[4], bf[4];
      #pragma unroll
      for (int i = 0; i < 4; ++i)
        af[i] = *(const bf16x8*)(smem + (wr * 64 + i * 16 + fr) * 128 + ((kk * 64 + fb) ^ sw));
      #pragma unroll
      for (int j = 0; j < 4; ++j)
        bf[j] = *(const bf16x8*)(smem + 16384 + (wc * 64 + j * 16 + fr) * 128 + ((kk * 64 + fb) ^ sw));
      #pragma unroll
      for (int i = 0; i < 4; ++i)
        #pragma unroll
        for (int j = 0; j < 4; ++j)
          acc[i][j] = __builtin_amdgcn_mfma_f32_16x16x32_bf16(af[i], bf[j], acc[i][j], 0, 0, 0);
    }
  }

  __syncthreads();  // all LDS tile reads done before epilogue reuse

  if constexpr (MODE == 0) {
    unsigned short* sm = (unsigned short*)smem;   // [128][136]
    float bcol[4];
    #pragma unroll
    for (int j = 0; j < 4; ++j) bcol[j] = bias[n0 + wc * 64 + j * 16 + fr];
    #pragma unroll
    for (int i = 0; i < 4; ++i)
      #pragma unroll
      for (int j = 0; j < 4; ++j)
        #pragma unroll
        for (int r = 0; r < 4; ++r)
          sm[(wr * 64 + i * 16 + g4 + r) * 136 + wc * 64 + j * 16 + fr] =
              f2bf((acc[i][j][r] + bcol[j]) * SQC);
    __syncthreads();
    unsigned short* o = (unsigned short*)outp;
    #pragma unroll
    for (int it = 0; it < 8; ++it) {
      const int cid = it * 256 + t;
      const int row = cid >> 4, ch = cid & 15;
      *(uint4v*)(o + (size_t)(m0 + row) * 1024 + n0 + ch * 8) =
          *(const uint4v*)(sm + row * 136 + ch * 8);
    }
  } else if constexpr (MODE == 1) {
    float* smf = (float*)smem;                    // [64][132]
    float bcol[4];
    #pragma unroll
    for (int j = 0; j < 4; ++j) bcol[j] = bias[n0 + wc * 64 + j * 16 + fr];
    float* o = (float*)outp;
    for (int half = 0; half < 2; ++half) {
      if (wr == half) {
        #pragma unroll
        for (int i = 0; i < 4; ++i)
          #pragma unroll
          for (int j = 0; j < 4; ++j)
            #pragma unroll
            for (int r = 0; r < 4; ++r)
              smf[(i * 16 + g4 + r) * 132 + wc * 64 + j * 16 + fr] = acc[i][j][r] + bcol[j];
      }
      __syncthreads();
      #pragma unroll
      for (int it = 0; it < 8; ++it) {
        const int cid = it * 256 + t;
        const int row = cid >> 5, ch = cid & 31;
        const int grow = m0 + half * 64 + row;
        if (grow < MROWS)
          *(float4v*)(o + (size_t)grow * 1024 + n0 + ch * 4) =
              *(const float4v*)(smf + row * 132 + ch * 4);
      }
      __syncthreads();
    }
  } else {  // MODE 2: rows = channels, cols = tokens; store channel-major into vt
    unsigned short* sm = (unsigned short*)smem;   // [128][136]
    float brow[4][4];
    #pragma unroll
    for (int i = 0; i < 4; ++i)
      #pragma unroll
      for (int r = 0; r < 4; ++r) brow[i][r] = bias[m0 + wr * 64 + i * 16 + g4 + r];
    #pragma unroll
    for (int i = 0; i < 4; ++i)
      #pragma unroll
      for (int j = 0; j < 4; ++j)
        #pragma unroll
        for (int r = 0; r < 4; ++r)
          sm[(wr * 64 + i * 16 + g4 + r) * 136 + wc * 64 + j * 16 + fr] =
              f2bf(acc[i][j][r] + brow[i][r]);
    __syncthreads();
    unsigned short* o = (unsigned short*)outp;
    const int col = t & 127;
    const int token = n0 + col;
    const int rbase = t >> 7;   // 0 or 1
    if (token < MROWS) {
      const unsigned int nimg = (unsigned int)token / 577u;
      const int s = token - (int)(nimg * 577u);
      unsigned short* op = o + ((size_t)nimg * 1024 + m0 + rbase) * SPAD + s;
      const unsigned short* sp = sm + rbase * 136 + col;
      #pragma unroll 8
      for (int it = 0; it < 64; ++it)
        op[(size_t)it * 2 * SPAD] = sp[it * 2 * 136];
    }
  }
}

// ---------------- flash attention, k = q ('qq'), no-max softmax ----------------
// QBLK=128: each wave owns 2x16 q-rows; K/V LDS fragments read ONCE feed both
// halves (halves per-output LDS traffic). Double-buffered staging (T3-min).
// 1-D grid 2560, XCD-chunked: bid&7 -> XCD, nh-major within XCD.
__global__ __launch_bounds__(256) void attn_kernel(const unsigned short* __restrict__ qbuf,
                                                   const unsigned short* __restrict__ vt,
                                                   unsigned short* __restrict__ out) {
  __shared__ char smem[32768];  // buf b at b*16384: K 8KB, V^T 8KB
  const int t = threadIdx.x, w = t >> 6, l = t & 63;
  const int g = l >> 4, fr = l & 15;
  const int bid = blockIdx.x;
  const int xcd = bid & 7, idx = bid >> 3;
  const int nhl = idx / 5;
  const int qb = idx - nhl * 5;
  const int nh = xcd * 64 + nhl;
  const int n = nh >> 4, h = nh & 15;
  const size_t rowbase = (size_t)n * SEQ;
  const int sw = (l & 7) << 4;

  // Q B-fragments (pre-scaled by SQC in GEMM0), 2 halves of 16 q-rows each
  bf16x8 bq[2][2];
  #pragma unroll
  for (int half = 0; half < 2; ++half) {
    const unsigned short* qp =
        qbuf + (rowbase + qb * 128 + half * 64 + w * 16 + fr) * 1024 + h * 64 + g * 8;
    bq[half][0] = *(const bf16x8*)qp;
    bq[half][1] = *(const bf16x8*)(qp + 32);
  }

  const int srow = l >> 3;
  const int scolE = ((((l & 7) * 16) ^ ((srow & 7) << 4)) >> 1);
  const unsigned short* ksrc = qbuf + (rowbase + w * 16 + srow) * 1024 + h * 64 + scolE;
  const unsigned short* vsrc = vt + ((size_t)nh * 64 + w * 16 + srow) * SPAD + scolE;

  f32x4 acc[2][4];
  #pragma unroll
  for (int half = 0; half < 2; ++half)
    #pragma unroll
    for (int cf = 0; cf < 4; ++cf) acc[half][cf] = (f32x4)0.0f;
  float l_run[2] = {0.0f, 0.0f};

  // prologue: stage tile 0 into buf 0
  {
    char* kdst = smem + (w * 16) * 128;
    char* vdst = smem + 8192 + (w * 16) * 128;
    load_lds16(ksrc, kdst);
    load_lds16(ksrc + (size_t)8 * 1024, kdst + 1024);
    load_lds16(vsrc, vdst);
    load_lds16(vsrc + 8 * SPAD, vdst + 1024);
  }
  __syncthreads();   // compiler drains vmcnt(0) before barrier

  for (int kb = 0; kb < 10; ++kb) {
    const int b = kb & 1;
    const char* kbuf = smem + b * 16384;
    const char* vbuf = kbuf + 8192;

    if (kb < 9) {  // prefetch next tile into other buffer (overlaps with compute)
      char* kdst = smem + (b ^ 1) * 16384 + (w * 16) * 128;
      char* vdst = kdst + 8192;
      load_lds16(ksrc + (size_t)((kb + 1) * 64) * 1024, kdst);
      load_lds16(ksrc + (size_t)((kb + 1) * 64 + 8) * 1024, kdst + 1024);
      load_lds16(vsrc + (kb + 1) * 64, vdst);
      load_lds16(vsrc + 8 * SPAD + (kb + 1) * 64, vdst + 1024);
    }

    // S^T for both halves; K fragment (af) read once, feeds 2 MFMAs
    f32x4 s4[2][4];
    #pragma unroll
    for (int half = 0; half < 2; ++half)
      #pragma unroll
      for (int cf = 0; cf < 4; ++cf) s4[half][cf] = (f32x4)0.0f;
    #pragma unroll
    for (int kk = 0; kk < 2; ++kk)
      #pragma unroll
      for (int cf = 0; cf < 4; ++cf) {
        const bf16x8 af = *(const bf16x8*)(kbuf + (cf * 16 + fr) * 128 + ((kk * 64 + g * 16) ^ sw));
        s4[0][cf] = __builtin_amdgcn_mfma_f32_16x16x32_bf16(af, bq[0][kk], s4[0][cf], 0, 0, 0);
        s4[1][cf] = __builtin_amdgcn_mfma_f32_16x16x32_bf16(af, bq[1][kk], s4[1][cf], 0, 0, 0);
      }

    if (kb == 9) {  // 577 = 9*64 + 1: only s_local == 0 valid
      #pragma unroll
      for (int half = 0; half < 2; ++half) {
        #pragma unroll
        for (int cf = 0; cf < 4; ++cf)
          #pragma unroll
          for (int r = 0; r < 4; ++r)
            if (cf != 0 || r != 0) s4[half][cf][r] = -__builtin_inff();
        s4[half][0][0] = (g == 0) ? s4[half][0][0] : -__builtin_inff();
      }
    }

    // softmax (no max subtraction — bounded inputs, f32-safe) + P->A-frag permlanes
    bf16x8 ap[2][2];
    #pragma unroll
    for (int half = 0; half < 2; ++half) {
      float sum = 0.0f;
      #pragma unroll
      for (int cf = 0; cf < 4; ++cf)
        #pragma unroll
        for (int r = 0; r < 4; ++r) {
          const float p = __builtin_amdgcn_exp2f(s4[half][cf][r]);
          s4[half][cf][r] = p;
          sum += p;
        }
      sum += __shfl_xor(sum, 16);
      sum += __shfl_xor(sum, 32);
      l_run[half] += sum;

      unsigned int pka[4], pkb[4];
      #pragma unroll
      for (int cf = 0; cf < 4; ++cf) {
        asm("v_cvt_pk_bf16_f32 %0, %1, %2" : "=v"(pka[cf]) : "v"(s4[half][cf][0]), "v"(s4[half][cf][1]));
        asm("v_cvt_pk_bf16_f32 %0, %1, %2" : "=v"(pkb[cf]) : "v"(s4[half][cf][2]), "v"(s4[half][cf][3]));
      }
      #pragma unroll
      for (int kk = 0; kk < 2; ++kk) {
        unsigned int a0 = pka[2 * kk], b0 = pka[2 * kk + 1];
        unsigned int a1 = pkb[2 * kk], b1 = pkb[2 * kk + 1];
        asm("v_permlane32_swap_b32 %0, %1" : "+v"(a0), "+v"(b0));
        asm("v_permlane16_swap_b32 %0, %1" : "+v"(a0), "+v"(b0));
        asm("v_permlane32_swap_b32 %0, %1" : "+v"(a1), "+v"(b1));
        asm("v_permlane16_swap_b32 %0, %1" : "+v"(a1), "+v"(b1));
        union { unsigned int i[4]; bf16x8 v; } u;
        u.i[0] = a0; u.i[1] = a1; u.i[2] = b0; u.i[3] = b1;
        ap[half][kk] = u.v;
      }
    }

    // PV: V fragment (bv) read once, feeds 2 MFMAs
    #pragma unroll
    for (int kk = 0; kk < 2; ++kk)
      #pragma unroll
      for (int cf = 0; cf < 4; ++cf) {
        const bf16x8 bv = *(const bf16x8*)(vbuf + (cf * 16 + fr) * 128 + ((kk * 64 + g * 16) ^ sw));
        acc[0][cf] = __builtin_amdgcn_mfma_f32_16x16x32_bf16(ap[0][kk], bv, acc[0][cf], 0, 0, 0);
        acc[1][cf] = __builtin_amdgcn_mfma_f32_16x16x32_bf16(ap[1][kk], bv, acc[1][cf], 0, 0, 0);
      }

    __syncthreads();   // drains prefetch vmcnt(0); next iter's buffer ready
  }

  #pragma unroll
  for (int half = 0; half < 2; ++half) {
    const float rcp = 1.0f / l_run[half];
    #pragma unroll
    for (int r = 0; r < 4; ++r) {
      const float rr = __shfl(rcp, g * 4 + r);
      const int qg = qb * 128 + half * 64 + w * 16 + g * 4 + r;
      if (qg < SEQ) {
        #pragma unroll
        for (int cf = 0; cf < 4; ++cf)
          out[(rowbase + qg) * 1024 + h * 64 + cf * 16 + fr] = f2bf(acc[half][cf][r] * rr);
      }
    }
  }
}

extern "C" void kernel_launch(void* const* d_in, const int* in_sizes, int n_in,
                              void* d_out, int out_size, void* d_ws, size_t ws_size,
                              hipStream_t stream) {
  const float* x     = (const float*)d_in[0];
  const float* ln_g  = (const float*)d_in[1];
  const float* ln_b  = (const float*)d_in[2];
  const float* w_in  = (const float*)d_in[3];
  const float* b_in  = (const float*)d_in[4];
  const float* w_out = (const float*)d_in[5];
  const float* b_out = (const float*)d_in[6];

  unsigned short* z    = (unsigned short*)d_ws;            // [MPAD][1024] bf16; reused as attn_out
  unsigned short* qbuf = z + (size_t)MPAD * 1024;          // [MPAD][1024] bf16 (q = k, pre-scaled)
  unsigned short* vt   = qbuf + (size_t)MPAD * 1024;       // [32*1024][640] bf16 (V^T)
  unsigned short* wqv  = vt + (size_t)512 * 64 * SPAD;     // [2048][1024] bf16
  unsigned short* wo   = wqv + (size_t)2048 * 1024;        // [1024][1024] bf16

  hipMemsetAsync(vt, 0, (size_t)512 * 64 * SPAD * 2, stream);  // pad cols must be finite (NaN*0 hazard)
  ln_kernel<<<MPAD, 256, 0, stream>>>(x, ln_g, ln_b, z);
  conv_kernel<<<(W1ELEMS + W2ELEMS) / 1024, 256, 0, stream>>>(w_in, w_out, wqv, wo);
  gemm_kernel<0><<<dim3(8, 145), 256, 0, stream>>>(z, wqv, b_in, qbuf);
  gemm_kernel<2><<<dim3(145, 8), 256, 0, stream>>>(wqv + (size_t)1024 * 1024, z, b_in + 2048, vt);
  attn_kernel<<<2560, 256, 0, stream>>>(qbuf, vt, z);
  gemm_kernel<1><<<dim3(8, 145), 256, 0, stream>>>(z, wo, b_out, d_out);
}